// Round 7
// baseline (121.431 us; speedup 1.0000x reference)
//
#include <hip/hip_runtime.h>

#define NPTS 8192
#define BATCH 4
#define BLOCK 256
#define NQ 4                   // queries per thread
#define QPB (BLOCK * NQ)       // 1024 queries per block
#define QBLOCKS (NPTS / QPB)   // 8
#define GROUPS 16              // target groups (partial-min slots per query)
#define GRP_SHIFT 4
#define TPB (NPTS / GROUPS)    // 512 targets per block
#define PAIRS (TPB / 2)        // 256 target pairs

typedef float v2f __attribute__((ext_vector_type(2)));
typedef float v4f __attribute__((ext_vector_type(4)));

// ---------------------------------------------------------------------------
// chamfer: grid (QBLOCKS*GROUPS, BATCH, 2) = 1024 blocks (4 waves/SIMD).
// R7: packed-FMA asm body. R6 pinned the scalar stream (VGPR 36, 47 us)
// and closed the books: VALU issue = 24 us exact (7168 instr x 2cy x 4
// waves/SIMD), LDS pipe = ~20 us (4096 ds_read_b128/CU x ~12 cy), sum =
// measured. Scalar FMA wastes the datapath: v_pk_fma_f32 does 2 lanes per
// 2-cy slot. R7 pins 12 pk_fma per body (4 independent v2f chains, dep
// distance 4) -> VALU issue 13.7 us; v_min3 merges left in C (no freedom
// to mangle). tgtA/tgtB paired layout (R0) makes each b128 quad's aligned
// sub-pairs direct pk operands: tgtA[j]={x0,x1,y0,y1}, tgtB[j]={z0,z1,
// |q0|^2,|q1|^2}. LDS reads unchanged (1 b128 per target).
// Plain partial-min stores per (query, group); no atomics, no memset.
// Block (0,0,0) zeroes out[0]. Workspace: 2*B*GROUPS*NPTS floats = 4 MiB.
// ---------------------------------------------------------------------------

// 2 targets x 4 query-chains, packed: d(v2f) = sq2 + mx*qx2 + my*qy2 + mz*qz2
// where m* = -2*p (splat). 12 v_pk_fma_f32, phase-grouped (dep distance 4).
#define BODYPK(TA, TB)                                                        \
  {                                                                           \
    const v2f qx2 = __builtin_shufflevector((TA), (TA), 0, 1);                \
    const v2f qy2 = __builtin_shufflevector((TA), (TA), 2, 3);                \
    const v2f qz2 = __builtin_shufflevector((TB), (TB), 0, 1);                \
    const v2f sq2 = __builtin_shufflevector((TB), (TB), 2, 3);                \
    v2f d0, d1, d2, d3;                                                       \
    asm("v_pk_fma_f32 %[d0], %[mx0], %[qx], %[sq]\n\t"                       \
        "v_pk_fma_f32 %[d1], %[mx1], %[qx], %[sq]\n\t"                       \
        "v_pk_fma_f32 %[d2], %[mx2], %[qx], %[sq]\n\t"                       \
        "v_pk_fma_f32 %[d3], %[mx3], %[qx], %[sq]\n\t"                       \
        "v_pk_fma_f32 %[d0], %[my0], %[qy], %[d0]\n\t"                       \
        "v_pk_fma_f32 %[d1], %[my1], %[qy], %[d1]\n\t"                       \
        "v_pk_fma_f32 %[d2], %[my2], %[qy], %[d2]\n\t"                       \
        "v_pk_fma_f32 %[d3], %[my3], %[qy], %[d3]\n\t"                       \
        "v_pk_fma_f32 %[d0], %[mz0], %[qz], %[d0]\n\t"                       \
        "v_pk_fma_f32 %[d1], %[mz1], %[qz], %[d1]\n\t"                       \
        "v_pk_fma_f32 %[d2], %[mz2], %[qz], %[d2]\n\t"                       \
        "v_pk_fma_f32 %[d3], %[mz3], %[qz], %[d3]"                           \
        : [d0] "=&v"(d0), [d1] "=&v"(d1), [d2] "=&v"(d2), [d3] "=&v"(d3)      \
        : [qx] "v"(qx2), [qy] "v"(qy2), [qz] "v"(qz2), [sq] "v"(sq2),         \
          [mx0] "v"(mx0), [mx1] "v"(mx1), [mx2] "v"(mx2), [mx3] "v"(mx3),     \
          [my0] "v"(my0), [my1] "v"(my1), [my2] "v"(my2), [my3] "v"(my3),     \
          [mz0] "v"(mz0), [mz1] "v"(mz1), [mz2] "v"(mz2), [mz3] "v"(mz3));    \
    best0 = fminf(best0, fminf(d0[0], d0[1]));  /* v_min3_f32 */              \
    best1 = fminf(best1, fminf(d1[0], d1[1]));                                \
    best2 = fminf(best2, fminf(d2[0], d2[1]));                                \
    best3 = fminf(best3, fminf(d3[0], d3[1]));                                \
  }

__global__ __launch_bounds__(256, 4) void chamfer_kernel(
    const float* __restrict__ x, const float* __restrict__ y,
    float* __restrict__ mins, float* __restrict__ out) {
    __shared__ v4f tgtA[PAIRS];
    __shared__ v4f tgtB[PAIRS];

    if (blockIdx.x == 0 && blockIdx.y == 0 && blockIdx.z == 0 && threadIdx.x == 0)
        out[0] = 0.0f;

    const int dir = blockIdx.z;
    const int b = blockIdx.y;
    const int g = blockIdx.x & (GROUPS - 1);
    const int qb = blockIdx.x >> GRP_SHIFT;

    const float* pts = dir ? y : x;  // query set
    const float* oth = dir ? x : y;  // target set

    // stage 512 targets: each thread owns one PAIR (points 2t,2t+1; 24 B)
    {
        const int t = threadIdx.x;
        const float* q = oth + ((size_t)b * NPTS + g * TPB + 2 * t) * 3;
        const float qx0 = q[0], qy0 = q[1], qz0 = q[2];
        const float qx1 = q[3], qy1 = q[4], qz1 = q[5];
        const float sq0 = fmaf(qz0, qz0, fmaf(qy0, qy0, qx0 * qx0));
        const float sq1 = fmaf(qz1, qz1, fmaf(qy1, qy1, qx1 * qx1));
        tgtA[t] = (v4f){qx0, qx1, qy0, qy1};
        tgtB[t] = (v4f){qz0, qz1, sq0, sq1};
    }

    // query splats: -2*p duplicated into v2f (pk operands); |p|^2 at store.
    v2f mx0, mx1, mx2, mx3, my0, my1, my2, my3, mz0, mz1, mz2, mz3;
    float sp0, sp1, sp2, sp3;
    float best0 = 3.0e38f, best1 = 3.0e38f, best2 = 3.0e38f, best3 = 3.0e38f;
    const int qbase = b * NPTS + qb * QPB + (int)threadIdx.x;
    {
        const float* p0 = pts + (size_t)(qbase + 0 * BLOCK) * 3;
        const float* p1 = pts + (size_t)(qbase + 1 * BLOCK) * 3;
        const float* p2 = pts + (size_t)(qbase + 2 * BLOCK) * 3;
        const float* p3 = pts + (size_t)(qbase + 3 * BLOCK) * 3;
        float px, py, pz;
        px = p0[0]; py = p0[1]; pz = p0[2];
        mx0 = (v2f){-2.0f * px, -2.0f * px};
        my0 = (v2f){-2.0f * py, -2.0f * py};
        mz0 = (v2f){-2.0f * pz, -2.0f * pz};
        sp0 = fmaf(pz, pz, fmaf(py, py, px * px));
        px = p1[0]; py = p1[1]; pz = p1[2];
        mx1 = (v2f){-2.0f * px, -2.0f * px};
        my1 = (v2f){-2.0f * py, -2.0f * py};
        mz1 = (v2f){-2.0f * pz, -2.0f * pz};
        sp1 = fmaf(pz, pz, fmaf(py, py, px * px));
        px = p2[0]; py = p2[1]; pz = p2[2];
        mx2 = (v2f){-2.0f * px, -2.0f * px};
        my2 = (v2f){-2.0f * py, -2.0f * py};
        mz2 = (v2f){-2.0f * pz, -2.0f * pz};
        sp2 = fmaf(pz, pz, fmaf(py, py, px * px));
        px = p3[0]; py = p3[1]; pz = p3[2];
        mx3 = (v2f){-2.0f * px, -2.0f * px};
        my3 = (v2f){-2.0f * py, -2.0f * py};
        mz3 = (v2f){-2.0f * pz, -2.0f * pz};
        sp3 = fmaf(pz, pz, fmaf(py, py, px * px));
    }

    __syncthreads();

    // 4 pairs (8 targets) per iteration; all 8 quads loaded up front so
    // later pairs' ds_read latency hides under earlier asm bodies.
#pragma unroll 1
    for (int j = 0; j < PAIRS; j += 4) {
        const v4f a0 = tgtA[j],     b0 = tgtB[j];
        const v4f a1 = tgtA[j + 1], b1 = tgtB[j + 1];
        const v4f a2 = tgtA[j + 2], b2 = tgtB[j + 2];
        const v4f a3 = tgtA[j + 3], b3 = tgtB[j + 3];
        BODYPK(a0, b0);
        BODYPK(a1, b1);
        BODYPK(a2, b2);
        BODYPK(a3, b3);
    }

    // plain coalesced stores of this group's partial min per query
    float* om = mins + ((size_t)((dir * BATCH + b) * GROUPS + g)) * NPTS +
                qb * QPB + threadIdx.x;
    om[0 * BLOCK] = fmaxf(sp0 + best0, 0.0f);
    om[1 * BLOCK] = fmaxf(sp1 + best1, 0.0f);
    om[2 * BLOCK] = fmaxf(sp2 + best2, 0.0f);
    om[3 * BLOCK] = fmaxf(sp3 + best3, 0.0f);
}

// ---------------------------------------------------------------------------
// finalize: 64 blocks x 256 threads. Each thread owns 4 adjacent queries of
// one (dir,b) slice: min-reduces the 16 group partials (float4 loads,
// coalesced within each group slice), sums the 4 mins * 1/(B*N) -- the
// exact same sum tree as before. gid 0 adds the regularizer. Block reduce
// + atomicAdd into out[0].
// ---------------------------------------------------------------------------
__global__ __launch_bounds__(256) void finalize_kernel(
    const float* __restrict__ mins, const float* __restrict__ R,
    const float* __restrict__ S, const float* __restrict__ t,
    const float* __restrict__ R_gt, const float* __restrict__ S_gt,
    const float* __restrict__ t_gt, float* __restrict__ out) {
    const float4* m4 = (const float4*)mins;  // [8][GROUPS][NPTS/4]
    const int gid = blockIdx.x * 256 + (int)threadIdx.x;  // 0..16383
    const int db = gid >> 11;       // dir*BATCH+b, 0..7
    const int qi = gid & 2047;      // float4 index within slice

    float4 mn = m4[(size_t)(db * GROUPS) * (NPTS / 4) + qi];
#pragma unroll
    for (int gg = 1; gg < GROUPS; ++gg) {
        const float4 u = m4[(size_t)(db * GROUPS + gg) * (NPTS / 4) + qi];
        mn.x = fminf(mn.x, u.x);
        mn.y = fminf(mn.y, u.y);
        mn.z = fminf(mn.z, u.z);
        mn.w = fminf(mn.w, u.w);
    }
    float v = (mn.x + mn.y + mn.z + mn.w) * (1.0f / (BATCH * NPTS));

    if (gid == 0) {
        float acc = 0.0f;
        for (int b = 0; b < BATCH; ++b)
            for (int i = 0; i < 3; ++i)
                for (int k = 0; k < 3; ++k) {
                    float s = 0.0f;
                    for (int j = 0; j < 3; ++j)
                        s += R_gt[b * 9 + j * 3 + i] * R[b * 9 + j * 3 + k];
                    s -= (i == k) ? 1.0f : 0.0f;
                    acc += s * s;
                }
        for (int d = 0; d < 3; ++d)  // jnp.diagonal(S, axis1=0, axis2=1)
            for (int a = 0; a < 3; ++a) {
                const float diff = S[d * 9 + d * 3 + a] - S_gt[d * 9 + d * 3 + a];
                acc += diff * diff;
            }
        for (int b = 0; b < BATCH; ++b)
            for (int k = 0; k < 3; ++k) {
                const float diff = t[b * 3 + k] - t_gt[b * 3 + k];
                acc += diff * diff;
            }
        v += acc;
    }

    // block reduction: 4 waves of 64
    for (int off = 32; off; off >>= 1) v += __shfl_down(v, off, 64);
    __shared__ float wsum[4];
    const int lane = threadIdx.x & 63;
    const int wave = threadIdx.x >> 6;
    if (lane == 0) wsum[wave] = v;
    __syncthreads();
    if (wave == 0) {
        v = (lane < 4) ? wsum[lane] : 0.0f;
        for (int off = 2; off; off >>= 1) v += __shfl_down(v, off, 64);
        if (lane == 0) atomicAdd(out, v);
    }
}

extern "C" void kernel_launch(void* const* d_in, const int* in_sizes, int n_in,
                              void* d_out, int out_size, void* d_ws, size_t ws_size,
                              hipStream_t stream) {
    const float* x    = (const float*)d_in[0];
    const float* y    = (const float*)d_in[1];
    const float* R    = (const float*)d_in[2];
    const float* S    = (const float*)d_in[3];
    const float* t    = (const float*)d_in[4];
    const float* R_gt = (const float*)d_in[5];
    const float* S_gt = (const float*)d_in[6];
    const float* t_gt = (const float*)d_in[7];
    float* out = (float*)d_out;
    float* mins = (float*)d_ws;  // 2*BATCH*GROUPS*NPTS floats = 4 MiB

    chamfer_kernel<<<dim3(QBLOCKS * GROUPS, BATCH, 2), dim3(BLOCK), 0, stream>>>(
        x, y, mins, out);

    finalize_kernel<<<dim3(2 * BATCH * NPTS / 4 / 256), dim3(BLOCK), 0, stream>>>(
        mins, R, S, t, R_gt, S_gt, t_gt, out);
}

// Round 8
// 111.576 us; speedup vs baseline: 1.0883x; 1.0883x over previous
//
#include <hip/hip_runtime.h>

#define NPTS 8192
#define BATCH 4
#define BLOCK 256
#define NQ 8                   // queries per thread
#define QPB (BLOCK * NQ)       // 2048 queries per block
#define QBLOCKS (NPTS / QPB)   // 4
#define GROUPS 32              // target groups (partial-min slots per query)
#define GRP_SHIFT 5
#define TPB (NPTS / GROUPS)    // 256 targets per block

// ---------------------------------------------------------------------------
// chamfer: grid (QBLOCKS*GROUPS, BATCH, 2) = 1024 blocks = exactly 4
// blocks/CU (16 waves/CU, 4/SIMD), fully resident, no churn.
// R8 synthesis. Model that fits R0-R7: dur = max(VALU, LDS-return) + tax.
//  - VALU floor (6 fma + 1 min3 per 2 pairs): 57.3k cy/SIMD = 23.9 us.
//    R6's asm-pinned scalar body achieved this exactly (scalar fma = 2cy;
//    R7 proved v_pk_fma_f32 = 4cy, i.e. pk has NO cycle advantage).
//  - LDS return path: broadcast ds_read_b128 writes 64 lanes x 16 B ->
//    ~12 cy/CU. Reads = pairs/(64*NQ): NQ=4 -> 41 us (R6/R7 LDS-bound);
//    NQ=8 -> 20.5 us, under the VALU floor.
// R8 = R6's proven 28-op asm body (VGPR-pinned, no compiler mangling),
// called twice per target pair (queries 0-3, 4-7), NQ=8, TPB=256.
// LDS: tgt[t] = {x, y, z, |q|^2}; wave-uniform b128 broadcast reads.
// Plain partial-min stores per (query, group); no atomics, no memset.
// Block (0,0,0) zeroes out[0]. Workspace: 2*B*GROUPS*NPTS floats = 8 MiB.
// ---------------------------------------------------------------------------

// 2 targets x 4 query-chains: d = |q|^2 - 2 p.q  (sp=|p|^2 added at store).
// Phase-grouped: 8 chains advance one component per phase -> dep distance 8.
// Identical instruction stream to R6 (proven model-exact), parameterized by
// query index so it can cover queries i0..i3 of the NQ=8 state.
#define BODY4(T0, T1, i0, i1, i2, i3)                                         \
  {                                                                           \
    float d00, d01, d02, d03, d10, d11, d12, d13;                             \
    asm volatile(                                                             \
        "v_fma_f32 %[d00], %[nxa], %[t0x], %[t0w]\n\t"                        \
        "v_fma_f32 %[d10], %[nxa], %[t1x], %[t1w]\n\t"                        \
        "v_fma_f32 %[d01], %[nxb], %[t0x], %[t0w]\n\t"                        \
        "v_fma_f32 %[d11], %[nxb], %[t1x], %[t1w]\n\t"                        \
        "v_fma_f32 %[d02], %[nxc], %[t0x], %[t0w]\n\t"                        \
        "v_fma_f32 %[d12], %[nxc], %[t1x], %[t1w]\n\t"                        \
        "v_fma_f32 %[d03], %[nxd], %[t0x], %[t0w]\n\t"                        \
        "v_fma_f32 %[d13], %[nxd], %[t1x], %[t1w]\n\t"                        \
        "v_fmac_f32 %[d00], %[nya], %[t0y]\n\t"                               \
        "v_fmac_f32 %[d10], %[nya], %[t1y]\n\t"                               \
        "v_fmac_f32 %[d01], %[nyb], %[t0y]\n\t"                               \
        "v_fmac_f32 %[d11], %[nyb], %[t1y]\n\t"                               \
        "v_fmac_f32 %[d02], %[nyc], %[t0y]\n\t"                               \
        "v_fmac_f32 %[d12], %[nyc], %[t1y]\n\t"                               \
        "v_fmac_f32 %[d03], %[nyd], %[t0y]\n\t"                               \
        "v_fmac_f32 %[d13], %[nyd], %[t1y]\n\t"                               \
        "v_fmac_f32 %[d00], %[nza], %[t0z]\n\t"                               \
        "v_fmac_f32 %[d10], %[nza], %[t1z]\n\t"                               \
        "v_fmac_f32 %[d01], %[nzb], %[t0z]\n\t"                               \
        "v_fmac_f32 %[d11], %[nzb], %[t1z]\n\t"                               \
        "v_fmac_f32 %[d02], %[nzc], %[t0z]\n\t"                               \
        "v_fmac_f32 %[d12], %[nzc], %[t1z]\n\t"                               \
        "v_fmac_f32 %[d03], %[nzd], %[t0z]\n\t"                               \
        "v_fmac_f32 %[d13], %[nzd], %[t1z]\n\t"                               \
        "v_min3_f32 %[b0], %[b0], %[d00], %[d10]\n\t"                         \
        "v_min3_f32 %[b1], %[b1], %[d01], %[d11]\n\t"                         \
        "v_min3_f32 %[b2], %[b2], %[d02], %[d12]\n\t"                         \
        "v_min3_f32 %[b3], %[b3], %[d03], %[d13]"                             \
        : [b0] "+v"(best##i0), [b1] "+v"(best##i1), [b2] "+v"(best##i2),      \
          [b3] "+v"(best##i3), [d00] "=&v"(d00), [d01] "=&v"(d01),            \
          [d02] "=&v"(d02), [d03] "=&v"(d03), [d10] "=&v"(d10),               \
          [d11] "=&v"(d11), [d12] "=&v"(d12), [d13] "=&v"(d13)                \
        : [t0x] "v"((T0).x), [t0y] "v"((T0).y), [t0z] "v"((T0).z),            \
          [t0w] "v"((T0).w), [t1x] "v"((T1).x), [t1y] "v"((T1).y),            \
          [t1z] "v"((T1).z), [t1w] "v"((T1).w), [nxa] "v"(nx##i0),            \
          [nxb] "v"(nx##i1), [nxc] "v"(nx##i2), [nxd] "v"(nx##i3),            \
          [nya] "v"(ny##i0), [nyb] "v"(ny##i1), [nyc] "v"(ny##i2),            \
          [nyd] "v"(ny##i3), [nza] "v"(nz##i0), [nzb] "v"(nz##i1),            \
          [nzc] "v"(nz##i2), [nzd] "v"(nz##i3));                              \
  }

#define LOADQ(k)                                                              \
    {                                                                         \
        const float* p = pts + (size_t)(qbase + (k) * BLOCK) * 3;             \
        const float px = p[0], py = p[1], pz = p[2];                          \
        nx##k = -2.0f * px; ny##k = -2.0f * py; nz##k = -2.0f * pz;           \
        sp##k = fmaf(pz, pz, fmaf(py, py, px * px));                          \
    }

__global__ __launch_bounds__(256, 4) void chamfer_kernel(
    const float* __restrict__ x, const float* __restrict__ y,
    float* __restrict__ mins, float* __restrict__ out) {
    __shared__ float4 tgt[TPB];

    if (blockIdx.x == 0 && blockIdx.y == 0 && blockIdx.z == 0 && threadIdx.x == 0)
        out[0] = 0.0f;

    const int dir = blockIdx.z;
    const int b = blockIdx.y;
    const int g = blockIdx.x & (GROUPS - 1);
    const int qb = blockIdx.x >> GRP_SHIFT;

    const float* pts = dir ? y : x;  // query set
    const float* oth = dir ? x : y;  // target set

    // stage 256 targets: one per thread (12 B coalesced read -> 16 B quad)
    {
        const int t = threadIdx.x;
        const float* q = oth + ((size_t)b * NPTS + g * TPB + t) * 3;
        const float qx = q[0], qy = q[1], qz = q[2];
        const float sq = fmaf(qz, qz, fmaf(qy, qy, qx * qx));
        tgt[t] = (float4){qx, qy, qz, sq};
    }

    // query splats: -2*p per component (scalar), |p|^2 folded in at store.
    float nx0, nx1, nx2, nx3, nx4, nx5, nx6, nx7;
    float ny0, ny1, ny2, ny3, ny4, ny5, ny6, ny7;
    float nz0, nz1, nz2, nz3, nz4, nz5, nz6, nz7;
    float sp0, sp1, sp2, sp3, sp4, sp5, sp6, sp7;
    float best0 = 3.0e38f, best1 = 3.0e38f, best2 = 3.0e38f, best3 = 3.0e38f;
    float best4 = 3.0e38f, best5 = 3.0e38f, best6 = 3.0e38f, best7 = 3.0e38f;
    const int qbase = b * NPTS + qb * QPB + (int)threadIdx.x;
    LOADQ(0) LOADQ(1) LOADQ(2) LOADQ(3) LOADQ(4) LOADQ(5) LOADQ(6) LOADQ(7)

    __syncthreads();

    // 8 targets (4 pairs) per iteration; all 8 quads loaded up front so
    // later pairs' ds_read latency hides under earlier asm bodies.
#pragma unroll 1
    for (int j = 0; j < TPB; j += 8) {
        const float4 ta = tgt[j],     tb = tgt[j + 1];
        const float4 tc = tgt[j + 2], td = tgt[j + 3];
        const float4 te = tgt[j + 4], tf = tgt[j + 5];
        const float4 tg = tgt[j + 6], th = tgt[j + 7];
        BODY4(ta, tb, 0, 1, 2, 3);
        BODY4(ta, tb, 4, 5, 6, 7);
        BODY4(tc, td, 0, 1, 2, 3);
        BODY4(tc, td, 4, 5, 6, 7);
        BODY4(te, tf, 0, 1, 2, 3);
        BODY4(te, tf, 4, 5, 6, 7);
        BODY4(tg, th, 0, 1, 2, 3);
        BODY4(tg, th, 4, 5, 6, 7);
    }

    // plain coalesced stores of this group's partial min per query
    float* om = mins + ((size_t)((dir * BATCH + b) * GROUPS + g)) * NPTS +
                qb * QPB + threadIdx.x;
    om[0 * BLOCK] = fmaxf(sp0 + best0, 0.0f);
    om[1 * BLOCK] = fmaxf(sp1 + best1, 0.0f);
    om[2 * BLOCK] = fmaxf(sp2 + best2, 0.0f);
    om[3 * BLOCK] = fmaxf(sp3 + best3, 0.0f);
    om[4 * BLOCK] = fmaxf(sp4 + best4, 0.0f);
    om[5 * BLOCK] = fmaxf(sp5 + best5, 0.0f);
    om[6 * BLOCK] = fmaxf(sp6 + best6, 0.0f);
    om[7 * BLOCK] = fmaxf(sp7 + best7, 0.0f);
}

// ---------------------------------------------------------------------------
// finalize: 64 blocks x 256 threads. Each thread owns 4 adjacent queries of
// one (dir,b) slice: min-reduces the 32 group partials (float4 loads,
// coalesced within each group slice), sums the 4 mins * 1/(B*N) -- the
// exact same sum tree as before. gid 0 adds the regularizer. Block reduce
// + atomicAdd into out[0].
// ---------------------------------------------------------------------------
__global__ __launch_bounds__(256) void finalize_kernel(
    const float* __restrict__ mins, const float* __restrict__ R,
    const float* __restrict__ S, const float* __restrict__ t,
    const float* __restrict__ R_gt, const float* __restrict__ S_gt,
    const float* __restrict__ t_gt, float* __restrict__ out) {
    const float4* m4 = (const float4*)mins;  // [8][GROUPS][NPTS/4]
    const int gid = blockIdx.x * 256 + (int)threadIdx.x;  // 0..16383
    const int db = gid >> 11;       // dir*BATCH+b, 0..7
    const int qi = gid & 2047;      // float4 index within slice

    float4 mn = m4[(size_t)(db * GROUPS) * (NPTS / 4) + qi];
#pragma unroll
    for (int gg = 1; gg < GROUPS; ++gg) {
        const float4 u = m4[(size_t)(db * GROUPS + gg) * (NPTS / 4) + qi];
        mn.x = fminf(mn.x, u.x);
        mn.y = fminf(mn.y, u.y);
        mn.z = fminf(mn.z, u.z);
        mn.w = fminf(mn.w, u.w);
    }
    float v = (mn.x + mn.y + mn.z + mn.w) * (1.0f / (BATCH * NPTS));

    if (gid == 0) {
        float acc = 0.0f;
        for (int b = 0; b < BATCH; ++b)
            for (int i = 0; i < 3; ++i)
                for (int k = 0; k < 3; ++k) {
                    float s = 0.0f;
                    for (int j = 0; j < 3; ++j)
                        s += R_gt[b * 9 + j * 3 + i] * R[b * 9 + j * 3 + k];
                    s -= (i == k) ? 1.0f : 0.0f;
                    acc += s * s;
                }
        for (int d = 0; d < 3; ++d)  // jnp.diagonal(S, axis1=0, axis2=1)
            for (int a = 0; a < 3; ++a) {
                const float diff = S[d * 9 + d * 3 + a] - S_gt[d * 9 + d * 3 + a];
                acc += diff * diff;
            }
        for (int b = 0; b < BATCH; ++b)
            for (int k = 0; k < 3; ++k) {
                const float diff = t[b * 3 + k] - t_gt[b * 3 + k];
                acc += diff * diff;
            }
        v += acc;
    }

    // block reduction: 4 waves of 64
    for (int off = 32; off; off >>= 1) v += __shfl_down(v, off, 64);
    __shared__ float wsum[4];
    const int lane = threadIdx.x & 63;
    const int wave = threadIdx.x >> 6;
    if (lane == 0) wsum[wave] = v;
    __syncthreads();
    if (wave == 0) {
        v = (lane < 4) ? wsum[lane] : 0.0f;
        for (int off = 2; off; off >>= 1) v += __shfl_down(v, off, 64);
        if (lane == 0) atomicAdd(out, v);
    }
}

extern "C" void kernel_launch(void* const* d_in, const int* in_sizes, int n_in,
                              void* d_out, int out_size, void* d_ws, size_t ws_size,
                              hipStream_t stream) {
    const float* x    = (const float*)d_in[0];
    const float* y    = (const float*)d_in[1];
    const float* R    = (const float*)d_in[2];
    const float* S    = (const float*)d_in[3];
    const float* t    = (const float*)d_in[4];
    const float* R_gt = (const float*)d_in[5];
    const float* S_gt = (const float*)d_in[6];
    const float* t_gt = (const float*)d_in[7];
    float* out = (float*)d_out;
    float* mins = (float*)d_ws;  // 2*BATCH*GROUPS*NPTS floats = 8 MiB

    chamfer_kernel<<<dim3(QBLOCKS * GROUPS, BATCH, 2), dim3(BLOCK), 0, stream>>>(
        x, y, mins, out);

    finalize_kernel<<<dim3(2 * BATCH * NPTS / 4 / 256), dim3(BLOCK), 0, stream>>>(
        mins, R, S, t, R_gt, S_gt, t_gt, out);
}